// Round 1
// baseline (1529.074 us; speedup 1.0000x reference)
//
#include <hip/hip_runtime.h>
#include <cstdint>
#include <math.h>

#define B_  64
#define L_  256
#define V_  256
#define E_  256
#define H_  1024
#define H3  3072

typedef __bf16 bf16x8 __attribute__((ext_vector_type(8)));
typedef float  f32x4  __attribute__((ext_vector_type(4)));

__device__ __forceinline__ unsigned short f2bf(float f) {
    union { float f; unsigned u; } v; v.f = f;
    unsigned r = v.u + 0x7fffu + ((v.u >> 16) & 1u);   // round-to-nearest-even
    return (unsigned short)(r >> 16);
}

// ok iff NO 16-bit half of any dword equals the 0xAAAA poison sentinel
__device__ __forceinline__ int chunk_ok(bf16x8 v) {
    union { bf16x8 b; unsigned u[4]; } cv; cv.b = v;
    int ok = 1;
#pragma unroll
    for (int i = 0; i < 4; i++) {
        unsigned x = cv.u[i] ^ 0xAAAAAAAAu;
        ok &= (int)((x & 0xFFFFu) != 0u) & (int)((x >> 16) != 0u);
    }
    return ok;
}

__device__ __forceinline__ float sigmoid_f(float x) {
    return __builtin_amdgcn_rcpf(1.0f + __expf(-x));
}
__device__ __forceinline__ float tanh_f(float x) {
    // tanh(x) = 1 - 2/(e^{2x}+1); saturates correctly at +-inf
    return 1.0f - 2.0f * __builtin_amdgcn_rcpf(1.0f + __expf(2.0f * x));
}

// ---- single prep kernel: 3 transposes + emb convert + h0 zero + hist poison ----
// grid regions: [0,3072) WhT tiles; [3072,3840) WiT; [3840,4096) WoutT;
// [4096,4352) embB+h0; [4352,12544) poison slots 1..256.
__global__ __launch_bounds__(256) void prep_all(
        const float* __restrict__ Wh, const float* __restrict__ Wi,
        const float* __restrict__ Wout, const float* __restrict__ emb,
        unsigned short* __restrict__ WhT, unsigned short* __restrict__ WiT,
        unsigned short* __restrict__ WoutT, unsigned short* __restrict__ embB,
        unsigned short* __restrict__ h0b, uint4* __restrict__ poison) {
    __shared__ unsigned short tile[32][34];
    int bid = blockIdx.x;
    const float* src; unsigned short* dst; int rows, cols, nt, kt;
    if (bid < 3072)      { src = Wh;   dst = WhT;   rows = H_; cols = H3; nt = bid % 96; kt = bid / 96; }
    else if (bid < 3840) { int b = bid - 3072; src = Wi;   dst = WiT;   rows = E_; cols = H3; nt = b % 96; kt = b / 96; }
    else if (bid < 4096) { int b = bid - 3840; src = Wout; dst = WoutT; rows = H_; cols = V_; nt = b % 8;  kt = b / 8; }
    else if (bid < 4352) {
        int idx = (bid - 4096) * 256 + threadIdx.x;   // 65536 = V*E = B*H
        embB[idx] = f2bf(emb[idx]);
        h0b[idx]  = 0;
        return;
    } else {
        size_t T = (size_t)(bid - 4352) * 256 + threadIdx.x;   // 2M uint4 = 33.55 MB
        uint4 v; v.x = v.y = v.z = v.w = 0xAAAAAAAAu;
        poison[T] = v;
        return;
    }
    int n0 = nt * 32, k0 = kt * 32;
    int tx = threadIdx.x & 31, ty = threadIdx.x >> 5;
#pragma unroll
    for (int j = 0; j < 32; j += 8)
        tile[tx][ty + j] = f2bf(src[(size_t)(k0 + ty + j) * cols + (n0 + tx)]);
    __syncthreads();
#pragma unroll
    for (int j = 0; j < 32; j += 8)
        dst[(size_t)(n0 + ty + j) * rows + (k0 + tx)] = tile[ty + j][tx];
}

// ---- phase 2: persistent GRU, XCD-local dataflow ----
// 4 batch-groups of 16 batches; group g = blocks with bid%8==g (one XCD under
// round-robin dispatch). Each block computes TWO 16x16 j-tiles (j0..j0+32)
// sharing the same polled h rows. Producer h-stores: plain (XCD L2) + sc0 sc1
// (L3 safety copy). Consumer polls: sc0 (L2) fast path; sticky fallback to
// sc0 sc1 coherent polls after 512 missed spins (correct under ANY mapping).
__global__ __launch_bounds__(256, 1) void gru_persistent(
        unsigned short* __restrict__ hist,        // [257][B][H], slot0=0, rest poisoned
        const unsigned short* __restrict__ WhT,   // [3H][H]
        const unsigned short* __restrict__ WiT,   // [3H][E]
        const unsigned short* __restrict__ embB,  // [V][E]
        const int* __restrict__ tokens,           // [B][L]
        const float* __restrict__ bh,
        unsigned short* __restrict__ yB) {        // [B][L][H]
    int bid = blockIdx.x;
    int g = bid & 7;
    if (g >= 4) return;                           // XCDs 4..7 idle (latency-bound)
    int jpair = bid >> 3;                         // 0..31
    int b0 = g * 16;
    int j0 = jpair * 32;

    __shared__ float red[4][2][4][64][4];         // [wave][tile][slot][lane][elem] 32 KB

    int wave = threadIdx.x >> 6, lane = threadIdx.x & 63;
    int l16 = lane & 15, q = lane >> 4;
    int kbase = wave * 256;

    // ---- pin Wh fragments for both tiles (192 regs; compiler may use AGPRs) ----
    bf16x8 Wreg[2][3][8];
#pragma unroll
    for (int tl = 0; tl < 2; tl++) {
#pragma unroll
        for (int g3 = 0; g3 < 3; g3++) {
            const bf16x8* Brow = (const bf16x8*)(WhT + (size_t)(g3 * H_ + j0 + tl * 16 + l16) * H_);
#pragma unroll
            for (int kk = 0; kk < 8; kk++) {
                Wreg[tl][g3][kk] = Brow[(kbase >> 3) + kk * 4 + q];
                asm volatile("" : "+v"(Wreg[tl][g3][kk]));
            }
        }
    }
    // ---- pin Wi fragments (48 regs) ----
    bf16x8 Wxreg[2][3][2];
#pragma unroll
    for (int tl = 0; tl < 2; tl++) {
#pragma unroll
        for (int g3 = 0; g3 < 3; g3++) {
            const bf16x8* Bx = (const bf16x8*)(WiT + (size_t)(g3 * H_ + j0 + tl * 16 + l16) * E_);
#pragma unroll
            for (int c = 0; c < 2; c++) {
                Wxreg[tl][g3][c] = Bx[wave * 8 + c * 4 + q];
                asm volatile("" : "+v"(Wxreg[tl][g3][c]));
            }
        }
    }

    // ---- per-thread gate mapping / biases / fp32 state ----
    int j_local = lane & 15;
    int b_local = (lane >> 4) * 4 + wave;         // C/D row = (lane>>4)*4 + elem
    int b = b0 + b_local;
    float bh_r[2], bh_z[2], bh_n[2];
#pragma unroll
    for (int tl = 0; tl < 2; tl++) {
        int jg = j0 + tl * 16 + j_local;
        bh_r[tl] = bh[jg];
        bh_z[tl] = bh[H_ + jg];
        bh_n[tl] = bh[2 * H_ + jg];
        asm volatile("" : "+v"(bh_r[tl]), "+v"(bh_z[tl]), "+v"(bh_n[tl]));
    }
    float hreg[2] = {0.0f, 0.0f};
    const int tokrow = (b0 + l16) * L_;
    int coh = 0;                                  // sticky coherent-poll fallback

    for (int t = 0; t < L_; t++) {
        const unsigned short* hist_t  = hist + (size_t)t * (B_ * H_);
        unsigned short*       hist_t1 = hist + (size_t)(t + 1) * (B_ * H_);

        // ---- xw partials seeded into accumulators (h-independent; pre-poll) ----
        int tok = tokens[tokrow + t];
        const bf16x8* Ax = (const bf16x8*)(embB + (size_t)tok * E_);
        bf16x8 ax0 = Ax[wave * 8 + q];
        bf16x8 ax1 = Ax[wave * 8 + 4 + q];
        f32x4 accr[2] = {}, accz[2] = {}, acchn[2] = {}, accxn[2] = {};
#pragma unroll
        for (int tl = 0; tl < 2; tl++) {
            accr[tl]  = __builtin_amdgcn_mfma_f32_16x16x32_bf16(ax0, Wxreg[tl][0][0], accr[tl], 0, 0, 0);
            accr[tl]  = __builtin_amdgcn_mfma_f32_16x16x32_bf16(ax1, Wxreg[tl][0][1], accr[tl], 0, 0, 0);
            accz[tl]  = __builtin_amdgcn_mfma_f32_16x16x32_bf16(ax0, Wxreg[tl][1][0], accz[tl], 0, 0, 0);
            accz[tl]  = __builtin_amdgcn_mfma_f32_16x16x32_bf16(ax1, Wxreg[tl][1][1], accz[tl], 0, 0, 0);
            accxn[tl] = __builtin_amdgcn_mfma_f32_16x16x32_bf16(ax0, Wxreg[tl][2][0], accxn[tl], 0, 0, 0);
            accxn[tl] = __builtin_amdgcn_mfma_f32_16x16x32_bf16(ax1, Wxreg[tl][2][1], accxn[tl], 0, 0, 0);
        }

        const unsigned short* p = hist_t + (size_t)(b0 + l16) * H_ + kbase + q * 8;
        bf16x8 a0, a1, a2, a3, a4, a5, a6, a7;

        // ---- poll group A (chunks 0-3); passing iteration = the data ----
        {
            int spins = 0;
            while (true) {
                if (coh) {
                    asm volatile("global_load_dwordx4 %0, %1, off sc0 sc1" : "=v"(a0) : "v"(p));
                    asm volatile("global_load_dwordx4 %0, %1, off sc0 sc1" : "=v"(a1) : "v"(p + 32));
                    asm volatile("global_load_dwordx4 %0, %1, off sc0 sc1" : "=v"(a2) : "v"(p + 64));
                    asm volatile("global_load_dwordx4 %0, %1, off sc0 sc1" : "=v"(a3) : "v"(p + 96));
                } else {
                    asm volatile("global_load_dwordx4 %0, %1, off sc0" : "=v"(a0) : "v"(p));
                    asm volatile("global_load_dwordx4 %0, %1, off sc0" : "=v"(a1) : "v"(p + 32));
                    asm volatile("global_load_dwordx4 %0, %1, off sc0" : "=v"(a2) : "v"(p + 64));
                    asm volatile("global_load_dwordx4 %0, %1, off sc0" : "=v"(a3) : "v"(p + 96));
                }
                asm volatile("s_waitcnt vmcnt(0)"
                             : "+v"(a0), "+v"(a1), "+v"(a2), "+v"(a3) :: "memory");
                int ok = chunk_ok(a0) & chunk_ok(a1) & chunk_ok(a2) & chunk_ok(a3);
                if (__all(ok)) break;
                ++spins;
                if (spins == 512) coh = 1;        // sticky: mapping assumption failed
                if (spins > (1 << 18)) break;     // fail loud, never hang
                if (coh) __builtin_amdgcn_s_sleep(1);
            }
        }
        // ---- issue group B loads; overlap with group-A MFMAs ----
        if (coh) {
            asm volatile("global_load_dwordx4 %0, %1, off sc0 sc1" : "=v"(a4) : "v"(p + 128));
            asm volatile("global_load_dwordx4 %0, %1, off sc0 sc1" : "=v"(a5) : "v"(p + 160));
            asm volatile("global_load_dwordx4 %0, %1, off sc0 sc1" : "=v"(a6) : "v"(p + 192));
            asm volatile("global_load_dwordx4 %0, %1, off sc0 sc1" : "=v"(a7) : "v"(p + 224));
        } else {
            asm volatile("global_load_dwordx4 %0, %1, off sc0" : "=v"(a4) : "v"(p + 128));
            asm volatile("global_load_dwordx4 %0, %1, off sc0" : "=v"(a5) : "v"(p + 160));
            asm volatile("global_load_dwordx4 %0, %1, off sc0" : "=v"(a6) : "v"(p + 192));
            asm volatile("global_load_dwordx4 %0, %1, off sc0" : "=v"(a7) : "v"(p + 224));
        }

#pragma unroll
        for (int tl = 0; tl < 2; tl++) {
            accr[tl]  = __builtin_amdgcn_mfma_f32_16x16x32_bf16(a0, Wreg[tl][0][0], accr[tl], 0, 0, 0);
            accr[tl]  = __builtin_amdgcn_mfma_f32_16x16x32_bf16(a1, Wreg[tl][0][1], accr[tl], 0, 0, 0);
            accr[tl]  = __builtin_amdgcn_mfma_f32_16x16x32_bf16(a2, Wreg[tl][0][2], accr[tl], 0, 0, 0);
            accr[tl]  = __builtin_amdgcn_mfma_f32_16x16x32_bf16(a3, Wreg[tl][0][3], accr[tl], 0, 0, 0);
            accz[tl]  = __builtin_amdgcn_mfma_f32_16x16x32_bf16(a0, Wreg[tl][1][0], accz[tl], 0, 0, 0);
            accz[tl]  = __builtin_amdgcn_mfma_f32_16x16x32_bf16(a1, Wreg[tl][1][1], accz[tl], 0, 0, 0);
            accz[tl]  = __builtin_amdgcn_mfma_f32_16x16x32_bf16(a2, Wreg[tl][1][2], accz[tl], 0, 0, 0);
            accz[tl]  = __builtin_amdgcn_mfma_f32_16x16x32_bf16(a3, Wreg[tl][1][3], accz[tl], 0, 0, 0);
            acchn[tl] = __builtin_amdgcn_mfma_f32_16x16x32_bf16(a0, Wreg[tl][2][0], acchn[tl], 0, 0, 0);
            acchn[tl] = __builtin_amdgcn_mfma_f32_16x16x32_bf16(a1, Wreg[tl][2][1], acchn[tl], 0, 0, 0);
            acchn[tl] = __builtin_amdgcn_mfma_f32_16x16x32_bf16(a2, Wreg[tl][2][2], acchn[tl], 0, 0, 0);
            acchn[tl] = __builtin_amdgcn_mfma_f32_16x16x32_bf16(a3, Wreg[tl][2][3], acchn[tl], 0, 0, 0);
        }

        // ---- wait + check group B; poll only B on miss ----
        asm volatile("s_waitcnt vmcnt(0)"
                     : "+v"(a4), "+v"(a5), "+v"(a6), "+v"(a7) :: "memory");
        {
            int ok = chunk_ok(a4) & chunk_ok(a5) & chunk_ok(a6) & chunk_ok(a7);
            if (!__all(ok)) {
                int spins = 0;
                while (true) {
                    if (coh) {
                        asm volatile("global_load_dwordx4 %0, %1, off sc0 sc1" : "=v"(a4) : "v"(p + 128));
                        asm volatile("global_load_dwordx4 %0, %1, off sc0 sc1" : "=v"(a5) : "v"(p + 160));
                        asm volatile("global_load_dwordx4 %0, %1, off sc0 sc1" : "=v"(a6) : "v"(p + 192));
                        asm volatile("global_load_dwordx4 %0, %1, off sc0 sc1" : "=v"(a7) : "v"(p + 224));
                    } else {
                        asm volatile("global_load_dwordx4 %0, %1, off sc0" : "=v"(a4) : "v"(p + 128));
                        asm volatile("global_load_dwordx4 %0, %1, off sc0" : "=v"(a5) : "v"(p + 160));
                        asm volatile("global_load_dwordx4 %0, %1, off sc0" : "=v"(a6) : "v"(p + 192));
                        asm volatile("global_load_dwordx4 %0, %1, off sc0" : "=v"(a7) : "v"(p + 224));
                    }
                    asm volatile("s_waitcnt vmcnt(0)"
                                 : "+v"(a4), "+v"(a5), "+v"(a6), "+v"(a7) :: "memory");
                    int ok2 = chunk_ok(a4) & chunk_ok(a5) & chunk_ok(a6) & chunk_ok(a7);
                    if (__all(ok2)) break;
                    ++spins;
                    if (spins == 512) coh = 1;
                    if (spins > (1 << 18)) break;
                    if (coh) __builtin_amdgcn_s_sleep(1);
                }
            }
        }
#pragma unroll
        for (int tl = 0; tl < 2; tl++) {
            accr[tl]  = __builtin_amdgcn_mfma_f32_16x16x32_bf16(a4, Wreg[tl][0][4], accr[tl], 0, 0, 0);
            accr[tl]  = __builtin_amdgcn_mfma_f32_16x16x32_bf16(a5, Wreg[tl][0][5], accr[tl], 0, 0, 0);
            accr[tl]  = __builtin_amdgcn_mfma_f32_16x16x32_bf16(a6, Wreg[tl][0][6], accr[tl], 0, 0, 0);
            accr[tl]  = __builtin_amdgcn_mfma_f32_16x16x32_bf16(a7, Wreg[tl][0][7], accr[tl], 0, 0, 0);
            accz[tl]  = __builtin_amdgcn_mfma_f32_16x16x32_bf16(a4, Wreg[tl][1][4], accz[tl], 0, 0, 0);
            accz[tl]  = __builtin_amdgcn_mfma_f32_16x16x32_bf16(a5, Wreg[tl][1][5], accz[tl], 0, 0, 0);
            accz[tl]  = __builtin_amdgcn_mfma_f32_16x16x32_bf16(a6, Wreg[tl][1][6], accz[tl], 0, 0, 0);
            accz[tl]  = __builtin_amdgcn_mfma_f32_16x16x32_bf16(a7, Wreg[tl][1][7], accz[tl], 0, 0, 0);
            acchn[tl] = __builtin_amdgcn_mfma_f32_16x16x32_bf16(a4, Wreg[tl][2][4], acchn[tl], 0, 0, 0);
            acchn[tl] = __builtin_amdgcn_mfma_f32_16x16x32_bf16(a5, Wreg[tl][2][5], acchn[tl], 0, 0, 0);
            acchn[tl] = __builtin_amdgcn_mfma_f32_16x16x32_bf16(a6, Wreg[tl][2][6], acchn[tl], 0, 0, 0);
            acchn[tl] = __builtin_amdgcn_mfma_f32_16x16x32_bf16(a7, Wreg[tl][2][7], acchn[tl], 0, 0, 0);
        }

        // ---- cross-wave K-reduction through LDS (2 barriers, no parity) ----
        __syncthreads();                          // WAR: previous step's reads done
#pragma unroll
        for (int tl = 0; tl < 2; tl++) {
            *(f32x4*)&red[wave][tl][0][lane][0] = accr[tl];
            *(f32x4*)&red[wave][tl][1][lane][0] = accz[tl];
            *(f32x4*)&red[wave][tl][2][lane][0] = acchn[tl];
            *(f32x4*)&red[wave][tl][3][lane][0] = accxn[tl];
        }
        __syncthreads();

#pragma unroll
        for (int tl = 0; tl < 2; tl++) {
            float s0 = 0.f, s1 = 0.f, s2 = 0.f, s3 = 0.f;
#pragma unroll
            for (int w = 0; w < 4; w++) {
                s0 += red[w][tl][0][lane][wave];
                s1 += red[w][tl][1][lane][wave];
                s2 += red[w][tl][2][lane][wave];
                s3 += red[w][tl][3][lane][wave];
            }
            float r = sigmoid_f(s0 + bh_r[tl]);           // xr+hr folded
            float z = sigmoid_f(s1 + bh_z[tl]);           // xz+hz folded
            float n = tanh_f(s3 + r * (s2 + bh_n[tl]));   // xn + r*(hn+bhn)
            float hnew = (1.0f - z) * n + z * hreg[tl];
            hreg[tl] = hnew;

            unsigned short hbv = f2bf(hnew);
            if (hbv == 0xAAAAu) hbv = 0xAAABu;            // never store the sentinel

            int jg = j0 + tl * 16 + j_local;
            unsigned short* hp = hist_t1 + (size_t)b * H_ + jg;
            unsigned hv32 = hbv;
            // L3 safety copy first (device-visible regardless of mapping)...
            asm volatile("global_store_short %0, %1, off sc0 sc1"
                         :: "v"(hp), "v"(hv32) : "memory");
            // ...then plain store: lands in this XCD's L2 for the fast sc0 polls
            asm volatile("global_store_short %0, %1, off"
                         :: "v"(hp), "v"(hv32) : "memory");
            yB[((size_t)b * L_ + t) * H_ + jg] = hbv;     // cached; consumed after kernel end
        }
    }
}

// ---- phase 3: logits[m][v] = y[m] @ Wout + bout   (M=16384, K=1024, N=256) ----
__global__ __launch_bounds__(256) void out_gemm(const unsigned short* __restrict__ yB,
                                                const unsigned short* __restrict__ WoutT,
                                                const float* __restrict__ bout,
                                                float* __restrict__ out) {
    int ntile = blockIdx.x;
    int mtile = blockIdx.y;
    int wave = threadIdx.x >> 6, lane = threadIdx.x & 63;
    int l16 = lane & 15, q = lane >> 4;

    int m = mtile * 64 + wave * 16 + l16;
    const bf16x8* Arow = (const bf16x8*)(yB + (size_t)m * H_);
    int n0 = ntile * 64;

    f32x4 acc[4] = {};
    for (int k0 = 0; k0 < H_; k0 += 32) {
        bf16x8 a = Arow[(k0 >> 3) + q];
#pragma unroll
        for (int j = 0; j < 4; j++) {
            const bf16x8* Brow = (const bf16x8*)(WoutT + (size_t)(n0 + j*16 + l16) * H_);
            bf16x8 b = Brow[(k0 >> 3) + q];
            acc[j] = __builtin_amdgcn_mfma_f32_16x16x32_bf16(a, b, acc[j], 0, 0, 0);
        }
    }
    int mrow = mtile * 64 + wave * 16 + q * 4;
#pragma unroll
    for (int j = 0; j < 4; j++) {
        int n = n0 + j * 16 + l16;
        float bias = bout[n];
#pragma unroll
        for (int r = 0; r < 4; r++)
            out[(size_t)(mrow + r) * V_ + n] = acc[j][r] + bias;
    }
}

extern "C" void kernel_launch(void* const* d_in, const int* in_sizes, int n_in,
                              void* d_out, int out_size, void* d_ws, size_t ws_size,
                              hipStream_t stream) {
    const int*   tokens = (const int*)  d_in[0];
    const float* emb    = (const float*)d_in[1];
    const float* Wi     = (const float*)d_in[2];
    const float* Wh     = (const float*)d_in[3];
    const float* bh     = (const float*)d_in[4];
    const float* Wout   = (const float*)d_in[5];
    const float* bout   = (const float*)d_in[6];
    float* out = (float*)d_out;

    char* ws = (char*)d_ws;
    size_t off = 0;
    auto alloc = [&](size_t bytes) -> void* {
        void* p = ws + off;
        off += (bytes + 255) & ~(size_t)255;
        return p;
    };
    unsigned short* WhT   = (unsigned short*)alloc((size_t)H3 * H_ * 2);   // 6 MB
    unsigned short* WiT   = (unsigned short*)alloc((size_t)H3 * E_ * 2);   // 1.5 MB
    unsigned short* WoutT = (unsigned short*)alloc((size_t)V_ * H_ * 2);   // 0.5 MB
    unsigned short* embB  = (unsigned short*)alloc((size_t)V_ * E_ * 2);   // 128 KB
    unsigned short* yB    = (unsigned short*)alloc((size_t)B_ * L_ * H_ * 2); // 32 MB
    unsigned short* hist  = (unsigned short*)alloc((size_t)(L_ + 1) * B_ * H_ * 2); // 33.7 MB

    prep_all<<<12544, 256, 0, stream>>>(Wh, Wi, Wout, emb, WhT, WiT, WoutT,
                                        embB, hist, (uint4*)(hist + (size_t)B_ * H_));

    {
        unsigned short* ah = hist;
        const unsigned short* aW = WhT; const unsigned short* aWx = WiT;
        const unsigned short* ae = embB; const int* at = tokens;
        const float* ab = bh; unsigned short* ay = yB;
        void* args[] = {&ah, &aW, &aWx, &ae, &at, &ab, &ay};
        hipError_t err = hipLaunchCooperativeKernel((void*)gru_persistent,
                                                    dim3(256), dim3(256), args, 0, stream);
        if (err != hipSuccess) {
            // fallback: plain launch; 256 blocks at 1 block/CU co-reside on 256 CUs,
            // and all spins are bounded (fail loud via absmax, not hang)
            gru_persistent<<<dim3(256), dim3(256), 0, stream>>>(
                ah, aW, aWx, ae, at, ab, ay);
        }
    }

    out_gemm<<<dim3(4, 256), 256, 0, stream>>>(yB, WoutT, bout, out);
}

// Round 3
// 1091.466 us; speedup vs baseline: 1.4009x; 1.4009x over previous
//
#include <hip/hip_runtime.h>
#include <cstdint>
#include <math.h>

#define B_  64
#define L_  256
#define V_  256
#define E_  256
#define H_  1024
#define H3  3072

typedef __bf16 bf16x8 __attribute__((ext_vector_type(8)));
typedef float  f32x4  __attribute__((ext_vector_type(4)));
typedef unsigned u32x4 __attribute__((ext_vector_type(4)));

__device__ __forceinline__ unsigned short f2bf(float f) {
    union { float f; unsigned u; } v; v.f = f;
    unsigned r = v.u + 0x7fffu + ((v.u >> 16) & 1u);   // round-to-nearest-even
    return (unsigned short)(r >> 16);
}

// Producer writes each 16B chunk with ONE dwordx4 sc0 sc1 store (atomic
// visibility at L3), so checking dword0's two halves against the poison
// sentinel suffices to validate the whole chunk.
__device__ __forceinline__ int head_ok(bf16x8 v) {
    union { bf16x8 b; unsigned u[4]; } cv; cv.b = v;
    unsigned x = cv.u[0];
    return (int)((x & 0xFFFFu) != 0xAAAAu) & (int)((x >> 16) != 0xAAAAu);
}

// ---- single prep kernel: 3 transposes + emb convert + h0 zero + hist poison ----
// grid regions: [0,3072) WhT tiles; [3072,3840) WiT; [3840,4096) WoutT;
// [4096,4352) embB+h0; [4352,12544) poison slots 1..256.
__global__ __launch_bounds__(256) void prep_all(
        const float* __restrict__ Wh, const float* __restrict__ Wi,
        const float* __restrict__ Wout, const float* __restrict__ emb,
        unsigned short* __restrict__ WhT, unsigned short* __restrict__ WiT,
        unsigned short* __restrict__ WoutT, unsigned short* __restrict__ embB,
        unsigned short* __restrict__ h0b, uint4* __restrict__ poison) {
    __shared__ unsigned short tile[32][34];
    int bid = blockIdx.x;
    const float* src; unsigned short* dst; int rows, cols, nt, kt;
    if (bid < 3072)      { src = Wh;   dst = WhT;   rows = H_; cols = H3; nt = bid % 96; kt = bid / 96; }
    else if (bid < 3840) { int b = bid - 3072; src = Wi;   dst = WiT;   rows = E_; cols = H3; nt = b % 96; kt = b / 96; }
    else if (bid < 4096) { int b = bid - 3840; src = Wout; dst = WoutT; rows = H_; cols = V_; nt = b % 8;  kt = b / 8; }
    else if (bid < 4352) {
        int idx = (bid - 4096) * 256 + threadIdx.x;   // 65536 = V*E = B*H
        embB[idx] = f2bf(emb[idx]);
        h0b[idx]  = 0;
        return;
    } else {
        size_t T = (size_t)(bid - 4352) * 256 + threadIdx.x;   // 2M uint4 = 33.55 MB
        uint4 v; v.x = v.y = v.z = v.w = 0xAAAAAAAAu;
        poison[T] = v;
        return;
    }
    int n0 = nt * 32, k0 = kt * 32;
    int tx = threadIdx.x & 31, ty = threadIdx.x >> 5;
#pragma unroll
    for (int j = 0; j < 32; j += 8)
        tile[tx][ty + j] = f2bf(src[(size_t)(k0 + ty + j) * cols + (n0 + tx)]);
    __syncthreads();
#pragma unroll
    for (int j = 0; j < 32; j += 8)
        dst[(size_t)(n0 + ty + j) * rows + (k0 + tx)] = tile[ty + j][tx];
}

// ---- phase 2: persistent GRU; round-0 topology (sc0 sc1 both sides),
//      with: all-8 poll issued before xw MFMAs, dword0-only chunk checks,
//      wide (dwordx4) producer stores via LDS htile, next-step tok/emb
//      prefetch, no sleep for first 16 spins. ----
__global__ __launch_bounds__(256, 1) void gru_persistent(
        unsigned short* __restrict__ hist,        // [257][B][H], slot0=0, rest poisoned
        const unsigned short* __restrict__ WhT,   // [3H][H]
        const unsigned short* __restrict__ WiT,   // [3H][E]
        const unsigned short* __restrict__ embB,  // [V][E]
        const int* __restrict__ tokens,           // [B][L]
        const float* __restrict__ bh,
        unsigned short* __restrict__ yB) {        // [B][L][H]
    __shared__ f32x4 red[2][4][6][64];            // [parity][wave][slot][lane] 48 KB (zero-conflict layout)
    __shared__ unsigned short htile[16][24];      // 16x16 h staging, 48B row stride (16B-aligned halves)

    int bid = blockIdx.x;
    int btile = bid & 3;
    int jtile = bid >> 2;
    int wave = threadIdx.x >> 6, lane = threadIdx.x & 63;
    int l16 = lane & 15, q = lane >> 4;
    int b0 = btile * 16, j0 = jtile * 16;
    int kbase = wave * 256;

    // ---- pin Wh fragments (96 VGPR/lane) ----
    bf16x8 Wreg[3][8];
#pragma unroll
    for (int g = 0; g < 3; g++) {
        const bf16x8* Brow = (const bf16x8*)(WhT + (size_t)(g * H_ + j0 + l16) * H_);
#pragma unroll
        for (int kk = 0; kk < 8; kk++) {
            Wreg[g][kk] = Brow[(kbase >> 3) + kk * 4 + q];
            asm volatile("" : "+v"(Wreg[g][kk]));
        }
    }
    // ---- pin Wi fragments (24 VGPR/lane) ----
    bf16x8 Wxreg[3][2];
#pragma unroll
    for (int g = 0; g < 3; g++) {
        const bf16x8* Bx = (const bf16x8*)(WiT + (size_t)(g * H_ + j0 + l16) * E_);
#pragma unroll
        for (int c = 0; c < 2; c++) {
            Wxreg[g][c] = Bx[wave * 8 + c * 4 + q];
            asm volatile("" : "+v"(Wxreg[g][c]));
        }
    }

    // ---- per-thread gate mapping / biases / fp32 state ----
    int Lp  = threadIdx.x & 63;
    int reg = threadIdx.x >> 6;
    int b_local = (Lp >> 4) * 4 + reg;
    int j_local = Lp & 15;
    float bhr = bh[j0 + j_local];
    float bhz = bh[H_ + j0 + j_local];
    float bhn = bh[2 * H_ + j0 + j_local];
    asm volatile("" : "+v"(bhr), "+v"(bhz), "+v"(bhn));
    float hreg = 0.0f;

    const int tokrow = (b0 + l16) * L_;
    // storer role: 8 lanes per wave -> 32 wide stores per block-step
    int srow  = wave * 4 + ((lane >> 1) & 3);
    int shalf = lane & 1;

    // ---- bootstrap prefetch for t=0 ----
    int tok = tokens[tokrow];
    const bf16x8* Ax0p = (const bf16x8*)(embB + (size_t)tok * E_);
    bf16x8 ax0 = Ax0p[wave * 8 + q];
    bf16x8 ax1 = Ax0p[wave * 8 + 4 + q];

    for (int t = 0; t < L_; t++) {
        const unsigned short* hist_t  = hist + (size_t)t * (B_ * H_);
        unsigned short*       hist_t1 = hist + (size_t)(t + 1) * (B_ * H_);
        const unsigned short* p = hist_t + (size_t)(b0 + l16) * H_ + kbase + q * 8;

        bf16x8 a0, a1, a2, a3, a4, a5, a6, a7;
        // ---- issue ALL 8 poll loads first; xw work runs in their shadow ----
        asm volatile("global_load_dwordx4 %0, %1, off sc0 sc1" : "=v"(a0) : "v"(p));
        asm volatile("global_load_dwordx4 %0, %1, off sc0 sc1" : "=v"(a1) : "v"(p + 32));
        asm volatile("global_load_dwordx4 %0, %1, off sc0 sc1" : "=v"(a2) : "v"(p + 64));
        asm volatile("global_load_dwordx4 %0, %1, off sc0 sc1" : "=v"(a3) : "v"(p + 96));
        asm volatile("global_load_dwordx4 %0, %1, off sc0 sc1" : "=v"(a4) : "v"(p + 128));
        asm volatile("global_load_dwordx4 %0, %1, off sc0 sc1" : "=v"(a5) : "v"(p + 160));
        asm volatile("global_load_dwordx4 %0, %1, off sc0 sc1" : "=v"(a6) : "v"(p + 192));
        asm volatile("global_load_dwordx4 %0, %1, off sc0 sc1" : "=v"(a7) : "v"(p + 224));

        // ---- xw partials (h-independent; ax regs prefetched last step) ----
        f32x4 xacc[3] = {};
#pragma unroll
        for (int g = 0; g < 3; g++) {
            xacc[g] = __builtin_amdgcn_mfma_f32_16x16x32_bf16(ax0, Wxreg[g][0], xacc[g], 0, 0, 0);
            xacc[g] = __builtin_amdgcn_mfma_f32_16x16x32_bf16(ax1, Wxreg[g][1], xacc[g], 0, 0, 0);
        }
        // ---- prefetch next token id (plain cached load, asm-managed) ----
        int tnext = (t + 1 < L_) ? (t + 1) : (L_ - 1);
        const int* tp = tokens + tokrow + tnext;
        int tok_next;
        asm volatile("global_load_dword %0, %1, off" : "=v"(tok_next) : "v"(tp));

        // ---- poll: all 8 chunks, dword0-only check ----
        {
            int spins = 0;
            while (true) {
                asm volatile("s_waitcnt vmcnt(0)"
                             : "+v"(a0), "+v"(a1), "+v"(a2), "+v"(a3),
                               "+v"(a4), "+v"(a5), "+v"(a6), "+v"(a7), "+v"(tok_next)
                             :: "memory");
                int ok = head_ok(a0) & head_ok(a1) & head_ok(a2) & head_ok(a3)
                       & head_ok(a4) & head_ok(a5) & head_ok(a6) & head_ok(a7);
                if (__all(ok)) break;
                if (++spins > (1 << 18)) break;   // fail loud, never hang
                if (spins > 16) __builtin_amdgcn_s_sleep(1);
                asm volatile("global_load_dwordx4 %0, %1, off sc0 sc1" : "=v"(a0) : "v"(p));
                asm volatile("global_load_dwordx4 %0, %1, off sc0 sc1" : "=v"(a1) : "v"(p + 32));
                asm volatile("global_load_dwordx4 %0, %1, off sc0 sc1" : "=v"(a2) : "v"(p + 64));
                asm volatile("global_load_dwordx4 %0, %1, off sc0 sc1" : "=v"(a3) : "v"(p + 96));
                asm volatile("global_load_dwordx4 %0, %1, off sc0 sc1" : "=v"(a4) : "v"(p + 128));
                asm volatile("global_load_dwordx4 %0, %1, off sc0 sc1" : "=v"(a5) : "v"(p + 160));
                asm volatile("global_load_dwordx4 %0, %1, off sc0 sc1" : "=v"(a6) : "v"(p + 192));
                asm volatile("global_load_dwordx4 %0, %1, off sc0 sc1" : "=v"(a7) : "v"(p + 224));
            }
        }

        // ---- prefetch next emb row (lands during MFMAs/reduce) ----
        const bf16x8* Axn = (const bf16x8*)(embB + (size_t)tok_next * E_);
        bf16x8 ax0n, ax1n;
        asm volatile("global_load_dwordx4 %0, %1, off" : "=v"(ax0n) : "v"(Axn + wave * 8 + q));
        asm volatile("global_load_dwordx4 %0, %1, off" : "=v"(ax1n) : "v"(Axn + wave * 8 + 4 + q));

        // ---- 24 Wh MFMAs ----
        f32x4 acc[3] = {};
#pragma unroll
        for (int g = 0; g < 3; g++) {
            acc[g] = __builtin_amdgcn_mfma_f32_16x16x32_bf16(a0, Wreg[g][0], acc[g], 0, 0, 0);
            acc[g] = __builtin_amdgcn_mfma_f32_16x16x32_bf16(a1, Wreg[g][1], acc[g], 0, 0, 0);
            acc[g] = __builtin_amdgcn_mfma_f32_16x16x32_bf16(a2, Wreg[g][2], acc[g], 0, 0, 0);
            acc[g] = __builtin_amdgcn_mfma_f32_16x16x32_bf16(a3, Wreg[g][3], acc[g], 0, 0, 0);
            acc[g] = __builtin_amdgcn_mfma_f32_16x16x32_bf16(a4, Wreg[g][4], acc[g], 0, 0, 0);
            acc[g] = __builtin_amdgcn_mfma_f32_16x16x32_bf16(a5, Wreg[g][5], acc[g], 0, 0, 0);
            acc[g] = __builtin_amdgcn_mfma_f32_16x16x32_bf16(a6, Wreg[g][6], acc[g], 0, 0, 0);
            acc[g] = __builtin_amdgcn_mfma_f32_16x16x32_bf16(a7, Wreg[g][7], acc[g], 0, 0, 0);
        }

        // ---- parity LDS reduce (round-0 zero-conflict layout, one barrier) ----
        int par = t & 1;
#pragma unroll
        for (int g = 0; g < 3; g++) {
            red[par][wave][g][lane]     = acc[g];
            red[par][wave][3 + g][lane] = xacc[g];
        }
        __syncthreads();

        float gh0 = red[par][0][0][Lp][reg] + red[par][1][0][Lp][reg] + red[par][2][0][Lp][reg] + red[par][3][0][Lp][reg];
        float gh1 = red[par][0][1][Lp][reg] + red[par][1][1][Lp][reg] + red[par][2][1][Lp][reg] + red[par][3][1][Lp][reg];
        float gh2 = red[par][0][2][Lp][reg] + red[par][1][2][Lp][reg] + red[par][2][2][Lp][reg] + red[par][3][2][Lp][reg];
        float xr  = red[par][0][3][Lp][reg] + red[par][1][3][Lp][reg] + red[par][2][3][Lp][reg] + red[par][3][3][Lp][reg];
        float xz  = red[par][0][4][Lp][reg] + red[par][1][4][Lp][reg] + red[par][2][4][Lp][reg] + red[par][3][4][Lp][reg];
        float xn  = red[par][0][5][Lp][reg] + red[par][1][5][Lp][reg] + red[par][2][5][Lp][reg] + red[par][3][5][Lp][reg];

        float r = 1.0f / (1.0f + __expf(-(xr + gh0 + bhr)));
        float z = 1.0f / (1.0f + __expf(-(xz + gh1 + bhz)));
        float n = tanhf(xn + r * (gh2 + bhn));
        float hnew = (1.0f - z) * n + z * hreg;
        hreg = hnew;

        unsigned short hbv = f2bf(hnew);
        if (hbv == 0xAAAAu) hbv = 0xAAABu;   // never store the sentinel

        // ax_next are the only outstanding loads here (polls retired,
        // stores not yet issued): this wait is ~free and guarantees
        // ax0/ax1 validity for next step's xw MFMAs.
        asm volatile("s_waitcnt vmcnt(0)" : "+v"(ax0n), "+v"(ax1n) :: "memory");

        // ---- stage h tile in LDS; 32 lanes do 16B-atomic coherent stores ----
        htile[b_local][j_local] = hbv;
        __syncthreads();
        if (lane < 8) {
            u32x4 hv4 = *(const u32x4*)&htile[srow][shalf * 8];
            unsigned short* hp = hist_t1 + (size_t)(b0 + srow) * H_ + j0 + shalf * 8;
            asm volatile("global_store_dwordx4 %0, %1, off sc0 sc1"
                         :: "v"(hp), "v"(hv4) : "memory");
            unsigned short* yp = yB + ((size_t)(b0 + srow) * L_ + t) * H_ + j0 + shalf * 8;
            asm volatile("global_store_dwordx4 %0, %1, off"
                         :: "v"(yp), "v"(hv4) : "memory");
        }
        ax0 = ax0n; ax1 = ax1n;
    }
}

// ---- phase 3: logits[m][v] = y[m] @ Wout + bout   (M=16384, K=1024, N=256) ----
__global__ __launch_bounds__(256) void out_gemm(const unsigned short* __restrict__ yB,
                                                const unsigned short* __restrict__ WoutT,
                                                const float* __restrict__ bout,
                                                float* __restrict__ out) {
    int ntile = blockIdx.x;
    int mtile = blockIdx.y;
    int wave = threadIdx.x >> 6, lane = threadIdx.x & 63;
    int l16 = lane & 15, q = lane >> 4;

    int m = mtile * 64 + wave * 16 + l16;
    const bf16x8* Arow = (const bf16x8*)(yB + (size_t)m * H_);
    int n0 = ntile * 64;

    f32x4 acc[4] = {};
    for (int k0 = 0; k0 < H_; k0 += 32) {
        bf16x8 a = Arow[(k0 >> 3) + q];
#pragma unroll
        for (int j = 0; j < 4; j++) {
            const bf16x8* Brow = (const bf16x8*)(WoutT + (size_t)(n0 + j*16 + l16) * H_);
            bf16x8 b = Brow[(k0 >> 3) + q];
            acc[j] = __builtin_amdgcn_mfma_f32_16x16x32_bf16(a, b, acc[j], 0, 0, 0);
        }
    }
    int mrow = mtile * 64 + wave * 16 + q * 4;
#pragma unroll
    for (int j = 0; j < 4; j++) {
        int n = n0 + j * 16 + l16;
        float bias = bout[n];
#pragma unroll
        for (int r = 0; r < 4; r++)
            out[(size_t)(mrow + r) * V_ + n] = acc[j][r] + bias;
    }
}

extern "C" void kernel_launch(void* const* d_in, const int* in_sizes, int n_in,
                              void* d_out, int out_size, void* d_ws, size_t ws_size,
                              hipStream_t stream) {
    const int*   tokens = (const int*)  d_in[0];
    const float* emb    = (const float*)d_in[1];
    const float* Wi     = (const float*)d_in[2];
    const float* Wh     = (const float*)d_in[3];
    const float* bh     = (const float*)d_in[4];
    const float* Wout   = (const float*)d_in[5];
    const float* bout   = (const float*)d_in[6];
    float* out = (float*)d_out;

    char* ws = (char*)d_ws;
    size_t off = 0;
    auto alloc = [&](size_t bytes) -> void* {
        void* p = ws + off;
        off += (bytes + 255) & ~(size_t)255;
        return p;
    };
    unsigned short* WhT   = (unsigned short*)alloc((size_t)H3 * H_ * 2);   // 6 MB
    unsigned short* WiT   = (unsigned short*)alloc((size_t)H3 * E_ * 2);   // 1.5 MB
    unsigned short* WoutT = (unsigned short*)alloc((size_t)V_ * H_ * 2);   // 0.5 MB
    unsigned short* embB  = (unsigned short*)alloc((size_t)V_ * E_ * 2);   // 128 KB
    unsigned short* yB    = (unsigned short*)alloc((size_t)B_ * L_ * H_ * 2); // 32 MB
    unsigned short* hist  = (unsigned short*)alloc((size_t)(L_ + 1) * B_ * H_ * 2); // 33.7 MB

    prep_all<<<12544, 256, 0, stream>>>(Wh, Wi, Wout, emb, WhT, WiT, WoutT,
                                        embB, hist, (uint4*)(hist + (size_t)B_ * H_));

    {
        unsigned short* ah = hist;
        const unsigned short* aW = WhT; const unsigned short* aWx = WiT;
        const unsigned short* ae = embB; const int* at = tokens;
        const float* ab = bh; unsigned short* ay = yB;
        void* args[] = {&ah, &aW, &aWx, &ae, &at, &ab, &ay};
        hipError_t err = hipLaunchCooperativeKernel((void*)gru_persistent,
                                                    dim3(256), dim3(256), args, 0, stream);
        if (err != hipSuccess) {
            // fallback: plain launch; 256 blocks at 1 block/CU co-reside on 256 CUs,
            // and all spins are bounded (fail loud via absmax, not hang)
            gru_persistent<<<dim3(256), dim3(256), 0, stream>>>(
                ah, aW, aWx, ae, at, ab, ay);
        }
    }

    out_gemm<<<dim3(4, 256), 256, 0, stream>>>(yB, WoutT, bout, out);
}